// Round 1
// 293.003 us; speedup vs baseline: 1.0208x; 1.0208x over previous
//
#include <hip/hip_runtime.h>
#include <math.h>

// ---------------------------------------------------------------------------
// MultiChannelAttention on MI355X (gfx950)
// out = softmax(causal(rope(xWq^T) rope(xWk^T)^T / sqrt(C))) (xWv^T) Wf^T + b
// B=4 T=2048 C=1024. bf16 MFMA (16x16x32), fp32 accum.
// R9: proj_rope + final_gemm ported to a 128x256-tile, 512-thread, 8-wave
//     4-phase-per-K-tile core with COUNTED vmcnt(6) (T3+T4) + setprio (T5):
//     global_load_lds prefetch stays in flight across barriers (no vmcnt(0)
//     drain in steady state). XOR chunk-swizzle via pre-swizzled global
//     source (linear LDS dest) keeps ds_read_b128 conflict-free.
//     Exact grid fills: proj 768 blocks (=3x256 CUs), final 256 (=1x).
// R8: V projection computes Vt natively (A=Wv, B=x). R7: triangular score
//     grid; pv longest-K-first. R5: native v_sin/v_cos RoPE. R2: fused
//     exp-softmax (P=exp(s) bf16 + atomic row sums).
// Workspace layout (121 MB):
//   [0,16) xb  [16,24) Wq/Wk/Wv/Wf bf16  [24,40) Q  [40,56) K
//   [56,72) Vt  [72,88) O  [88,120) P bf16  [120,+32K) row_sum
// ---------------------------------------------------------------------------

#define AS1(p) ((__attribute__((address_space(1))) void*)(p))
#define AS3(p) ((__attribute__((address_space(3))) void*)(p))

typedef __attribute__((ext_vector_type(8))) short bf16x8;
typedef __attribute__((ext_vector_type(4))) float f32x4;

__device__ __forceinline__ unsigned short f2bf(float f) {
  unsigned int u = __float_as_uint(f);
  u += 0x7fffu + ((u >> 16) & 1u);   // round-to-nearest-even
  return (unsigned short)(u >> 16);
}

// ---- fp32 -> bf16 cast for x + 4 weight matrices, one launch --------------
__global__ __launch_bounds__(256) void cast_all(
    const float* __restrict__ x, const float* __restrict__ Wq,
    const float* __restrict__ Wk, const float* __restrict__ Wv,
    const float* __restrict__ Wf,
    unsigned short* __restrict__ xb, unsigned short* __restrict__ Wqb,
    unsigned short* __restrict__ Wkb, unsigned short* __restrict__ Wvb,
    unsigned short* __restrict__ Wfb) {
  int i = blockIdx.x * 256 + threadIdx.x;           // float4 index
  const float* src; unsigned short* dst; int off;
  if (i < 2097152) { src = x; dst = xb; off = i; }
  else {
    int j = i - 2097152;
    int w = j >> 18; off = j & 262143;              // 262144 float4 per W
    src = (w == 0) ? Wq : (w == 1) ? Wk : (w == 2) ? Wv : Wf;
    dst = (w == 0) ? Wqb : (w == 1) ? Wkb : (w == 2) ? Wvb : Wfb;
  }
  float4 f = ((const float4*)src)[off];
  ushort4 o;
  o.x = f2bf(f.x); o.y = f2bf(f.y); o.z = f2bf(f.z); o.w = f2bf(f.w);
  ((ushort4*)dst)[off] = o;
}

// ---- legacy 128x128 bt-GEMM core (256 thr), used by score_exp / pv_gemm ---
__device__ __forceinline__ void gemm_core(const unsigned short* __restrict__ At, long long lda,
                                          const unsigned short* __restrict__ Bt, long long ldb,
                                          int K, f32x4 (&acc)[4][4],
                                          unsigned short* As, unsigned short* Bs) {
  const int tid  = threadIdx.x;
  const int lane = tid & 63;
  const int w    = tid >> 6;
  const int wm   = (w & 1) << 6;
  const int wn   = (w >> 1) << 6;
  const int fr   = lane & 15;
  const int fq   = lane >> 4;
  const int srow = tid >> 2;
  const int scol = (tid & 3) << 3;
  const int lg   = ((tid & 3) ^ ((srow >> 1) & 3)) << 3;
  const unsigned short* a0 = At + (long long)srow * lda + lg;
  const unsigned short* a1 = At + (long long)(srow + 64) * lda + lg;
  const unsigned short* b0 = Bt + (long long)srow * ldb + lg;
  const unsigned short* b1 = Bt + (long long)(srow + 64) * ldb + lg;
  unsigned short* As0 = As + srow * 32 + scol;
  unsigned short* As1 = As + (srow + 64) * 32 + scol;
  unsigned short* Bs0 = Bs + srow * 32 + scol;
  unsigned short* Bs1 = Bs + (srow + 64) * 32 + scol;
  const int pg = (fq ^ ((fr >> 1) & 3)) << 3;
  for (int k0 = 0; k0 < K; k0 += 32) {
    __builtin_amdgcn_global_load_lds(AS1(a0 + k0), AS3(As0), 16, 0, 0);
    __builtin_amdgcn_global_load_lds(AS1(a1 + k0), AS3(As1), 16, 0, 0);
    __builtin_amdgcn_global_load_lds(AS1(b0 + k0), AS3(Bs0), 16, 0, 0);
    __builtin_amdgcn_global_load_lds(AS1(b1 + k0), AS3(Bs1), 16, 0, 0);
    __syncthreads();
    bf16x8 af[4], bfr[4];
#pragma unroll
    for (int i = 0; i < 4; i++)
      af[i] = *(const bf16x8*)(As + (wm + i * 16 + fr) * 32 + pg);
#pragma unroll
    for (int i = 0; i < 4; i++)
      bfr[i] = *(const bf16x8*)(Bs + (wn + i * 16 + fr) * 32 + pg);
#pragma unroll
    for (int mi = 0; mi < 4; mi++)
#pragma unroll
      for (int ni = 0; ni < 4; ni++)
        acc[mi][ni] = __builtin_amdgcn_mfma_f32_16x16x32_bf16(af[mi], bfr[ni], acc[mi][ni], 0, 0, 0);
    __syncthreads();
  }
}

// ---- LDS repack + coalesced bf16x8 store of one mi-slice (legacy) ---------
__device__ __forceinline__ void repack_store_mi(unsigned short (&vals)[4][4],
                                                unsigned short* sh, int mi,
                                                int m0, int n0, long long ldo,
                                                unsigned short* __restrict__ Out) {
  const int tid = threadIdx.x, lane = tid & 63, w = tid >> 6;
  const int half = w & 1, wn = (w >> 1) << 6;
  const int cl = lane & 15, q4 = lane >> 4;
  const int lr = half * 16 + q4 * 4;
#pragma unroll
  for (int ni = 0; ni < 4; ni++)
#pragma unroll
    for (int rr = 0; rr < 4; rr++)
      sh[(lr + rr) * 132 + wn + ni * 16 + cl] = vals[ni][rr];
  __syncthreads();
#pragma unroll
  for (int it = 0; it < 2; ++it) {
    int row = (tid >> 4) + it * 16;          // 0..31
    int c8 = (tid & 15) << 3;                // 0..120
    bf16x8 v = *(const bf16x8*)(sh + row * 132 + c8);
    int gr = m0 + (row < 16 ? mi * 16 + row : 48 + mi * 16 + row);
    *(bf16x8*)(Out + (long long)gr * ldo + n0 + c8) = v;
  }
  __syncthreads();
}

// ---------------------------------------------------------------------------
// NEW: 128x256-tile GEMM core. 512 threads = 8 waves (2 M-rows x 4 N-cols),
// per-wave 64x64 output (acc[4][4]). BK=64 per K-tile, 4 phases/K-tile,
// double-buffered LDS (96 KiB), counted vmcnt(6) gate once per K-tile.
// LDS layout (shorts): buf b at b*24576: A[128][64] at +0, B[256][64] at +8192.
// 16B-chunk swizzle: chunk ^= (row & 7); applied on the GLOBAL source for
// staging (LDS dest stays linear, as global_load_lds requires) and on the
// ds_read address. C[m,n] = sum_k A[m,k]*B[n,k], A/B bf16 K-fast.
// ---------------------------------------------------------------------------
__device__ __forceinline__ void core8(
    const unsigned short* __restrict__ A, long long lda,
    const unsigned short* __restrict__ B, long long ldb,
    int nkt, f32x4 (&acc)[4][4], unsigned short* lds) {
  const int tid  = threadIdx.x;
  const int lane = tid & 63;
  const int w    = tid >> 6;
  const int wr   = w >> 2;            // 0..1
  const int wc   = w & 3;             // 0..3
  const int fr   = lane & 15;
  const int fq   = lane >> 4;
  const int rsw0 = (fq ^ (fr & 7)) << 3;         // k-step 0 chunk (shorts)
  const int rsw1 = ((4 + fq) ^ (fr & 7)) << 3;   // k-step 1 chunk
  // staging: thread t covers LDS chunk (row = t>>3 per 64-row unit, chunk t&7)
  const int sr   = tid >> 3;                     // 0..63
  const int kswz = ((tid & 7) ^ (sr & 7)) << 3;  // pre-swizzled source chunk
  const unsigned short* Asrc = A + (long long)sr * lda + kswz;
  const unsigned short* Bsrc = B + (long long)sr * ldb + kswz;
  unsigned short* ldsw = lds + tid * 8;          // linear dest, 16B/thread

  auto stageA = [&](int b_, int kt_) {
    const unsigned short* s0 = Asrc + (long long)kt_ * 64;
    __builtin_amdgcn_global_load_lds(AS1(s0),            AS3(ldsw + b_ * 24576),         16, 0, 0);
    __builtin_amdgcn_global_load_lds(AS1(s0 + 64 * lda), AS3(ldsw + b_ * 24576 + 4096),  16, 0, 0);
  };
  auto stageB = [&](int b_, int kt_) {
    const unsigned short* s0 = Bsrc + (long long)kt_ * 64;
    __builtin_amdgcn_global_load_lds(AS1(s0),             AS3(ldsw + b_ * 24576 + 8192),  16, 0, 0);
    __builtin_amdgcn_global_load_lds(AS1(s0 + 64 * ldb),  AS3(ldsw + b_ * 24576 + 12288), 16, 0, 0);
    __builtin_amdgcn_global_load_lds(AS1(s0 + 128 * ldb), AS3(ldsw + b_ * 24576 + 16384), 16, 0, 0);
    __builtin_amdgcn_global_load_lds(AS1(s0 + 192 * ldb), AS3(ldsw + b_ * 24576 + 20480), 16, 0, 0);
  };

  // prologue: stage kt0 (buf0) + kt1 (buf1); gate leaves kt1's 6 in flight
  stageA(0, 0); stageB(0, 0);
  if (nkt > 1) {
    stageA(1, 1); stageB(1, 1);
    asm volatile("s_waitcnt vmcnt(6)" ::: "memory");
  } else {
    asm volatile("s_waitcnt vmcnt(0)" ::: "memory");
  }
  __builtin_amdgcn_s_barrier();

  const unsigned short* Ar = lds + (wr * 64 + fr) * 64;
  const unsigned short* Br = lds + 8192 + (wc * 64 + fr) * 64;

#define MFMA2(ACC, A0, A1, B0, B1)                                            \
  ACC = __builtin_amdgcn_mfma_f32_16x16x32_bf16(A0, B0, ACC, 0, 0, 0);        \
  ACC = __builtin_amdgcn_mfma_f32_16x16x32_bf16(A1, B1, ACC, 0, 0, 0);

#pragma unroll 1
  for (int kt = 0; kt < nkt; ++kt) {
    const int b = kt & 1;
    const unsigned short* Ab = Ar + b * 24576;
    const unsigned short* Bb = Br + b * 24576;
    bf16x8 aL[4], aH[4], bE[4], bO[4];
    // -------- phase 1: read A m0-1 + B n0-1; MFMA m0-1 x n0-1 --------
    aL[0] = *(const bf16x8*)(Ab + rsw0);
    aL[1] = *(const bf16x8*)(Ab + rsw1);
    aL[2] = *(const bf16x8*)(Ab + 1024 + rsw0);
    aL[3] = *(const bf16x8*)(Ab + 1024 + rsw1);
    bE[0] = *(const bf16x8*)(Bb + rsw0);
    bE[1] = *(const bf16x8*)(Bb + rsw1);
    bE[2] = *(const bf16x8*)(Bb + 1024 + rsw0);
    bE[3] = *(const bf16x8*)(Bb + 1024 + rsw1);
    __builtin_amdgcn_s_barrier();
    asm volatile("s_waitcnt lgkmcnt(0)" ::: "memory");
    __builtin_amdgcn_s_setprio(1);
    MFMA2(acc[0][0], aL[0], aL[1], bE[0], bE[1]);
    MFMA2(acc[0][1], aL[0], aL[1], bE[2], bE[3]);
    MFMA2(acc[1][0], aL[2], aL[3], bE[0], bE[1]);
    MFMA2(acc[1][1], aL[2], aL[3], bE[2], bE[3]);
    __builtin_amdgcn_s_setprio(0);
    __builtin_amdgcn_s_barrier();
    // -------- phase 2: read B n2-3; MFMA m0-1 x n2-3 --------
    bO[0] = *(const bf16x8*)(Bb + 2048 + rsw0);
    bO[1] = *(const bf16x8*)(Bb + 2048 + rsw1);
    bO[2] = *(const bf16x8*)(Bb + 3072 + rsw0);
    bO[3] = *(const bf16x8*)(Bb + 3072 + rsw1);
    __builtin_amdgcn_s_barrier();
    asm volatile("s_waitcnt lgkmcnt(0)" ::: "memory");
    __builtin_amdgcn_s_setprio(1);
    MFMA2(acc[0][2], aL[0], aL[1], bO[0], bO[1]);
    MFMA2(acc[0][3], aL[0], aL[1], bO[2], bO[3]);
    MFMA2(acc[1][2], aL[2], aL[3], bO[0], bO[1]);
    MFMA2(acc[1][3], aL[2], aL[3], bO[2], bO[3]);
    __builtin_amdgcn_s_setprio(0);
    __builtin_amdgcn_s_barrier();
    // -------- phase 3: read A m2-3; ISSUE B(kt+2); MFMA m2-3 x n0-1 --------
    // (B region of this buffer fully ds-read as of the ph2-end barrier)
    aH[0] = *(const bf16x8*)(Ab + 2048 + rsw0);
    aH[1] = *(const bf16x8*)(Ab + 2048 + rsw1);
    aH[2] = *(const bf16x8*)(Ab + 3072 + rsw0);
    aH[3] = *(const bf16x8*)(Ab + 3072 + rsw1);
    if (kt + 2 < nkt) stageB(b, kt + 2);
    __builtin_amdgcn_s_barrier();
    asm volatile("s_waitcnt lgkmcnt(0)" ::: "memory");
    __builtin_amdgcn_s_setprio(1);
    MFMA2(acc[2][0], aH[0], aH[1], bE[0], bE[1]);
    MFMA2(acc[2][1], aH[0], aH[1], bE[2], bE[3]);
    MFMA2(acc[3][0], aH[2], aH[3], bE[0], bE[1]);
    MFMA2(acc[3][1], aH[2], aH[3], bE[2], bE[3]);
    __builtin_amdgcn_s_setprio(0);
    __builtin_amdgcn_s_barrier();
    // -------- phase 4: ISSUE A(kt+2); counted gate for kt+1; MFMA m2-3 x n2-3
    if (kt + 2 < nkt) stageA(b, kt + 2);
    if (kt + 1 < nkt) {
      if (kt + 2 < nkt)
        asm volatile("s_waitcnt vmcnt(6)" ::: "memory");   // kt+1 landed; kt+2 in flight
      else
        asm volatile("s_waitcnt vmcnt(0)" ::: "memory");   // tail drain
    }
    __builtin_amdgcn_s_barrier();
    __builtin_amdgcn_s_setprio(1);
    MFMA2(acc[2][2], aH[0], aH[1], bO[0], bO[1]);
    MFMA2(acc[2][3], aH[0], aH[1], bO[2], bO[3]);
    MFMA2(acc[3][2], aH[2], aH[3], bO[0], bO[1]);
    MFMA2(acc[3][3], aH[2], aH[3], bO[2], bO[3]);
    __builtin_amdgcn_s_setprio(0);
    __builtin_amdgcn_s_barrier();
  }
#undef MFMA2
}

// ---- Q/K/V projections; Q/K get RoPE; V computed AS Vt (swapped operands) -
// Grid (64, 4, 3), 512 threads. Q/K: x=m-tile(128), y=n-tile(256).
// V: flat = x*4+y in [0,256): m-tile(d) = flat&7, n-tile(s) = flat>>3.
__global__ __launch_bounds__(512, 2) void proj_rope(
    const unsigned short* __restrict__ xb,
    const unsigned short* __restrict__ Wq, const unsigned short* __restrict__ Wk,
    const unsigned short* __restrict__ Wv,
    const float* __restrict__ bq, const float* __restrict__ bk, const float* __restrict__ bv,
    unsigned short* __restrict__ Q, unsigned short* __restrict__ Ko,
    unsigned short* __restrict__ Vt) {
  __shared__ unsigned short lds[49152];   // 96 KiB: GEMM dbuf, then repack
  const int which = blockIdx.z;
  const int tid = threadIdx.x, lane = tid & 63, w = tid >> 6;
  const int wr = w >> 2, wc = w & 3;
  const int cl = lane & 15, q4 = lane >> 4;

  f32x4 acc[4][4];
#pragma unroll
  for (int i = 0; i < 4; i++)
#pragma unroll
    for (int j = 0; j < 4; j++)
#pragma unroll
      for (int k = 0; k < 4; k++) acc[i][j][k] = 0.0f;

  if (which == 2) {
    // ---- V path: Vt[d,s] = sum_k Wv[d,k] x[s,k]; A = Wv (m=d), B = x (n=s)
    const int flat = blockIdx.x * 4 + blockIdx.y;   // 0..255
    const int m0 = (flat & 7) * 128;                // d tile
    const int n0 = (flat >> 3) * 256;               // global s tile
    core8(Wv + (long long)m0 * 1024, 1024, xb + (long long)n0 * 1024, 1024, 16, acc, lds);
    __syncthreads();
    const int b = n0 >> 11, sloc = n0 & 2047;
#pragma unroll
    for (int mi = 0; mi < 4; ++mi) {
      const int lr = wr * 64 + mi * 16 + q4 * 4;
#pragma unroll
      for (int rr = 0; rr < 4; ++rr) {
        const float b_ = bv[m0 + lr + rr];          // bias per d-row
#pragma unroll
        for (int nj = 0; nj < 4; ++nj)
          lds[(lr + rr) * 264 + wc * 64 + nj * 16 + cl] = f2bf(acc[mi][nj][rr] + b_);
      }
    }
    __syncthreads();
    unsigned short* Outb = Vt + (long long)b * 1024 * 2048;
#pragma unroll
    for (int it = 0; it < 8; ++it) {
      int c = it * 512 + tid;
      int row = c >> 5, c8 = (c & 31) << 3;
      bf16x8 v = *(const bf16x8*)(lds + row * 264 + c8);
      *(bf16x8*)(Outb + (long long)(m0 + row) * 2048 + sloc + c8) = v;
    }
    return;
  }

  // ---- Q/K path: bias + RoPE (native sin/cos) ----
  const int m0 = blockIdx.x * 128;    // token rows
  const int n0 = blockIdx.y * 256;    // feature cols
  const unsigned short* W = which == 0 ? Wq : Wk;
  const float* bias = which == 0 ? bq : bk;
  unsigned short* Out = which == 0 ? Q : Ko;

  core8(xb + (long long)m0 * 1024, 1024, W + (long long)n0 * 1024, 1024, 16, acc, lds);
  __syncthreads();

  const float NEG_L2T_512 = -0.025952563239354392f;  // -log2(10000)/512
  const float INV2PI = 0.15915494309189535f;
  float freqn[4];
#pragma unroll
  for (int nj = 0; nj < 4; ++nj) {
    int gn = n0 + wc * 64 + nj * 16 + cl;
    freqn[nj] = exp2f(NEG_L2T_512 * (float)(gn >> 1));
  }
#pragma unroll
  for (int mi = 0; mi < 4; ++mi) {
    const int lr = wr * 64 + mi * 16 + q4 * 4;
    const int t0 = (m0 & 2047) + lr;   // batch-local time (tiles never straddle)
#pragma unroll
    for (int nj = 0; nj < 4; ++nj) {
      const int gn = n0 + wc * 64 + nj * 16 + cl;
      const float bi = bias[gn];
#pragma unroll
      for (int rr = 0; rr < 4; ++rr) {
        float v = acc[mi][nj][rr] + bi;
        float partner = __shfl_xor(v, 1, 64);
        float ang = (float)(t0 + rr) * freqn[nj];
        float rev = ang * INV2PI;
        rev = rev - floorf(rev);           // v_sin/v_cos domain
        float c_ = __builtin_amdgcn_cosf(rev);
        float s_ = __builtin_amdgcn_sinf(rev);
        v = v * c_ + ((gn & 1) ? partner : -partner) * s_;
        lds[(lr + rr) * 264 + wc * 64 + nj * 16 + cl] = f2bf(v);
      }
    }
  }
  __syncthreads();
#pragma unroll
  for (int it = 0; it < 8; ++it) {
    int c = it * 512 + tid;
    int row = c >> 5, c8 = (c & 31) << 3;
    bf16x8 v = *(const bf16x8*)(lds + row * 264 + c8);
    *(bf16x8*)(Out + (long long)(m0 + row) * 1024 + n0 + c8) = v;
  }
}

// ---- P = exp(Q K^T / sqrt(C)) (causal-zeroed), bf16; row sums via atomics -
__global__ __launch_bounds__(256) void score_exp(const unsigned short* __restrict__ Q,
                                                 const unsigned short* __restrict__ Kk,
                                                 unsigned short* __restrict__ P,
                                                 float* __restrict__ row_sum) {
  __shared__ unsigned short sh[8192];
  const int bx = blockIdx.x;
  int i = (int)((sqrtf(8.0f * (float)bx + 1.0f) - 1.0f) * 0.5f);
  while ((i + 1) * (i + 2) / 2 <= bx) ++i;
  while (i * (i + 1) / 2 > bx) --i;
  const int j = bx - i * (i + 1) / 2;       // 0..i
  const int b = blockIdx.z;
  const int m0 = i * 128, n0 = j * 128;
  const unsigned short* Qb = Q + (long long)b * 2048 * 1024;
  const unsigned short* Kb = Kk + (long long)b * 2048 * 1024;
  unsigned short* Pb = P + (long long)b * 2048 * 2048;
  float* rs = row_sum + b * 2048;

  f32x4 acc[4][4];
#pragma unroll
  for (int ii = 0; ii < 4; ii++)
#pragma unroll
    for (int jj = 0; jj < 4; jj++)
#pragma unroll
      for (int k = 0; k < 4; k++) acc[ii][jj][k] = 0.0f;

  gemm_core(Qb + (long long)m0 * 1024, 1024, Kb + (long long)n0 * 1024, 1024, 1024, acc, sh, sh + 4096);

  const int tid = threadIdx.x, lane = tid & 63, w = tid >> 6;
  const int wm = (w & 1) << 6, wn = (w >> 1) << 6;
  const int cl = lane & 15, q4 = lane >> 4;
  const bool diag = (i == j);
#pragma unroll
  for (int mi = 0; mi < 4; mi++) {
    unsigned short vals[4][4];
    float rsum[4] = {0.f, 0.f, 0.f, 0.f};
#pragma unroll
    for (int ni = 0; ni < 4; ni++) {
      const int gn = n0 + wn + ni * 16 + cl;
#pragma unroll
      for (int rr = 0; rr < 4; rr++) {
        const int gm = m0 + wm + mi * 16 + q4 * 4 + rr;
        float e = (diag && gn > gm) ? 0.0f : __expf(acc[mi][ni][rr] * 0.03125f);
        vals[ni][rr] = f2bf(e);
        rsum[rr] += e;
      }
    }
#pragma unroll
    for (int rr = 0; rr < 4; rr++) {
#pragma unroll
      for (int off = 1; off < 16; off <<= 1) rsum[rr] += __shfl_xor(rsum[rr], off, 64);
    }
    if (cl == 0) {
      const int gm = m0 + wm + mi * 16 + q4 * 4;
#pragma unroll
      for (int rr = 0; rr < 4; rr++) atomicAdd(&rs[gm + rr], rsum[rr]);
    }
    repack_store_mi(vals, sh, mi, m0, n0, 2048, Pb);
  }
}

// ---- O = (P V) / row_sum; longest-K blocks dispatched first ---------------
__global__ __launch_bounds__(256) void pv_gemm(const unsigned short* __restrict__ P,
                                               const unsigned short* __restrict__ Vt,
                                               const float* __restrict__ row_sum,
                                               unsigned short* __restrict__ O) {
  __shared__ unsigned short sh[8192];
  const int b = blockIdx.z;
  const int mt = 15 - blockIdx.x;   // longest K first (tail balance)
  const int m0 = mt * 128;          // t tile
  const int n0 = blockIdx.y * 128;  // d tile
  const unsigned short* Pb = P + (long long)b * 2048 * 2048;
  const unsigned short* Vb = Vt + (long long)b * 1024 * 2048;
  const float* rs = row_sum + b * 2048;
  const int K = m0 + 128;  // causal: P[t, s>t] == 0 beyond this

  f32x4 acc[4][4];
#pragma unroll
  for (int i = 0; i < 4; i++)
#pragma unroll
    for (int j = 0; j < 4; j++)
#pragma unroll
      for (int k = 0; k < 4; k++) acc[i][j][k] = 0.0f;

  gemm_core(Pb + (long long)m0 * 2048, 2048, Vb + (long long)n0 * 2048, 2048, K, acc, sh, sh + 4096);

  const int tid = threadIdx.x, lane = tid & 63, w = tid >> 6;
  const int wm = (w & 1) << 6;
  const int q4 = lane >> 4;
#pragma unroll
  for (int mi = 0; mi < 4; mi++) {
    unsigned short vals[4][4];
    float inv[4];
    const int gm0 = m0 + wm + mi * 16 + q4 * 4;
#pragma unroll
    for (int rr = 0; rr < 4; rr++) inv[rr] = 1.0f / rs[gm0 + rr];
#pragma unroll
    for (int ni = 0; ni < 4; ni++)
#pragma unroll
      for (int rr = 0; rr < 4; rr++)
        vals[ni][rr] = f2bf(acc[mi][ni][rr] * inv[rr]);
    repack_store_mi(vals, sh, mi, m0, n0, 1024, O + (long long)b * 2048 * 1024);
  }
}

// ---- out = O Wf^T + bf, fp32 out (new 128x256 core, 512 thr) --------------
__global__ __launch_bounds__(512, 2) void final_gemm(const unsigned short* __restrict__ O,
                                                     const unsigned short* __restrict__ Wf,
                                                     const float* __restrict__ bf_,
                                                     float* __restrict__ out) {
  __shared__ unsigned short lds[49152];
  float* shf = (float*)lds;
  const int tid = threadIdx.x, lane = tid & 63, w = tid >> 6;
  const int wr = w >> 2, wc = w & 3;
  const int cl = lane & 15, q4 = lane >> 4;
  const int m0 = blockIdx.x * 128;
  const int n0 = blockIdx.y * 256;

  f32x4 acc[4][4];
#pragma unroll
  for (int i = 0; i < 4; i++)
#pragma unroll
    for (int j = 0; j < 4; j++)
#pragma unroll
      for (int k = 0; k < 4; k++) acc[i][j][k] = 0.0f;

  core8(O + (long long)m0 * 1024, 1024, Wf + (long long)n0 * 1024, 1024, 16, acc, lds);

  // fp32 repack in two 64-row rounds (64 x 260 floats = 66.5 KB <= 96 KB)
#pragma unroll
  for (int r = 0; r < 2; ++r) {
    __syncthreads();
    if (wr == r) {
#pragma unroll
      for (int mi = 0; mi < 4; ++mi)
#pragma unroll
        for (int nj = 0; nj < 4; ++nj) {
          const int col = wc * 64 + nj * 16 + cl;
          const float bi = bf_[n0 + col];
#pragma unroll
          for (int rr = 0; rr < 4; ++rr)
            shf[(mi * 16 + q4 * 4 + rr) * 260 + col] = acc[mi][nj][rr] + bi;
        }
    }
    __syncthreads();
#pragma unroll
    for (int it = 0; it < 8; ++it) {
      int c = it * 512 + tid;
      int row = c >> 6, c4 = (c & 63) << 2;
      float4 v = *(const float4*)(shf + row * 260 + c4);
      *(float4*)(out + (long long)(m0 + r * 64 + row) * 1024 + n0 + c4) = v;
    }
  }
}

// ---------------------------------------------------------------------------
extern "C" void kernel_launch(void* const* d_in, const int* in_sizes, int n_in,
                              void* d_out, int out_size, void* d_ws, size_t ws_size,
                              hipStream_t stream) {
  (void)in_sizes; (void)n_in; (void)out_size; (void)ws_size;
  const float* x   = (const float*)d_in[0];
  const float* Wq  = (const float*)d_in[1];
  const float* bq  = (const float*)d_in[2];
  const float* Wk  = (const float*)d_in[3];
  const float* bk  = (const float*)d_in[4];
  const float* Wv  = (const float*)d_in[5];
  const float* bv  = (const float*)d_in[6];
  const float* Wf  = (const float*)d_in[7];
  const float* bf_ = (const float*)d_in[8];
  float* out = (float*)d_out;

  char* ws = (char*)d_ws;
  const size_t MB = 1024 * 1024;
  unsigned short* xb  = (unsigned short*)(ws);             // 16 MB
  unsigned short* Wqb = (unsigned short*)(ws + 16 * MB);   // 2 MB
  unsigned short* Wkb = (unsigned short*)(ws + 18 * MB);   // 2 MB
  unsigned short* Wvb = (unsigned short*)(ws + 20 * MB);   // 2 MB
  unsigned short* Wfb = (unsigned short*)(ws + 22 * MB);   // 2 MB
  unsigned short* Qb  = (unsigned short*)(ws + 24 * MB);   // 16 MB
  unsigned short* Kb  = (unsigned short*)(ws + 40 * MB);   // 16 MB
  unsigned short* Vtb = (unsigned short*)(ws + 56 * MB);   // 16 MB
  unsigned short* Ob  = (unsigned short*)(ws + 72 * MB);   // 16 MB
  unsigned short* Pb  = (unsigned short*)(ws + 88 * MB);   // 32 MB P bf16
  float*          rsum= (float*)(ws + 120 * MB);           // 32 KB row sums

  hipMemsetAsync(rsum, 0, 8192 * sizeof(float), stream);
  cast_all<<<dim3(3145728 / 256), dim3(256), 0, stream>>>(x, Wq, Wk, Wv, Wf, xb, Wqb, Wkb, Wvb, Wfb);
  proj_rope<<<dim3(64, 4, 3), dim3(512), 0, stream>>>(xb, Wqb, Wkb, Wvb, bq, bk, bv, Qb, Kb, Vtb);
  score_exp<<<dim3(136, 1, 4), dim3(256), 0, stream>>>(Qb, Kb, Pb, rsum);
  pv_gemm<<<dim3(16, 8, 4), dim3(256), 0, stream>>>(Pb, Vtb, rsum, Ob);
  final_gemm<<<dim3(64, 4), dim3(512), 0, stream>>>(Ob, Wfb, bf_, out);
}

// Round 2
// 290.214 us; speedup vs baseline: 1.0306x; 1.0096x over previous
//
#include <hip/hip_runtime.h>
#include <math.h>

// ---------------------------------------------------------------------------
// MultiChannelAttention on MI355X (gfx950)
// out = softmax(causal(rope(xWq^T) rope(xWk^T)^T / sqrt(C))) (xWv^T) Wf^T + b
// B=4 T=2048 C=1024. bf16 MFMA (16x16x32), fp32 accum.
// R10: core8 restructured to 2 phases per K-tile split by k-step half
//      (16 MFMA / 8 ds_read per phase, 4 barriers/K-tile vs R9's 8).
//      LDS relayout [buf][k-half][rows][32] so halves stage independently;
//      counted vmcnt(6) certifies one half-tile ahead; stages issued
//      half-per-phase (sequential (tile,half) queue). Swizzle (row>>1)&3
//      on 16B chunks, pre-swizzled global source, linear LDS dest.
// R9: 128x256-tile 512-thread 8-wave core, counted vmcnt + setprio.
// R8: V projection computes Vt natively (A=Wv, B=x). R7: triangular score
//     grid; pv longest-K-first. R5: native v_sin/v_cos RoPE. R2: fused
//     exp-softmax (P=exp(s) bf16 + atomic row sums).
// Workspace layout (121 MB):
//   [0,16) xb  [16,24) Wq/Wk/Wv/Wf bf16  [24,40) Q  [40,56) K
//   [56,72) Vt  [72,88) O  [88,120) P bf16  [120,+32K) row_sum
// ---------------------------------------------------------------------------

#define AS1(p) ((__attribute__((address_space(1))) void*)(p))
#define AS3(p) ((__attribute__((address_space(3))) void*)(p))

typedef __attribute__((ext_vector_type(8))) short bf16x8;
typedef __attribute__((ext_vector_type(4))) float f32x4;

__device__ __forceinline__ unsigned short f2bf(float f) {
  unsigned int u = __float_as_uint(f);
  u += 0x7fffu + ((u >> 16) & 1u);   // round-to-nearest-even
  return (unsigned short)(u >> 16);
}

// ---- fp32 -> bf16 cast for x + 4 weight matrices, one launch --------------
__global__ __launch_bounds__(256) void cast_all(
    const float* __restrict__ x, const float* __restrict__ Wq,
    const float* __restrict__ Wk, const float* __restrict__ Wv,
    const float* __restrict__ Wf,
    unsigned short* __restrict__ xb, unsigned short* __restrict__ Wqb,
    unsigned short* __restrict__ Wkb, unsigned short* __restrict__ Wvb,
    unsigned short* __restrict__ Wfb) {
  int i = blockIdx.x * 256 + threadIdx.x;           // float4 index
  const float* src; unsigned short* dst; int off;
  if (i < 2097152) { src = x; dst = xb; off = i; }
  else {
    int j = i - 2097152;
    int w = j >> 18; off = j & 262143;              // 262144 float4 per W
    src = (w == 0) ? Wq : (w == 1) ? Wk : (w == 2) ? Wv : Wf;
    dst = (w == 0) ? Wqb : (w == 1) ? Wkb : (w == 2) ? Wvb : Wfb;
  }
  float4 f = ((const float4*)src)[off];
  ushort4 o;
  o.x = f2bf(f.x); o.y = f2bf(f.y); o.z = f2bf(f.z); o.w = f2bf(f.w);
  ((ushort4*)dst)[off] = o;
}

// ---- legacy 128x128 bt-GEMM core (256 thr), used by score_exp / pv_gemm ---
__device__ __forceinline__ void gemm_core(const unsigned short* __restrict__ At, long long lda,
                                          const unsigned short* __restrict__ Bt, long long ldb,
                                          int K, f32x4 (&acc)[4][4],
                                          unsigned short* As, unsigned short* Bs) {
  const int tid  = threadIdx.x;
  const int lane = tid & 63;
  const int w    = tid >> 6;
  const int wm   = (w & 1) << 6;
  const int wn   = (w >> 1) << 6;
  const int fr   = lane & 15;
  const int fq   = lane >> 4;
  const int srow = tid >> 2;
  const int scol = (tid & 3) << 3;
  const int lg   = ((tid & 3) ^ ((srow >> 1) & 3)) << 3;
  const unsigned short* a0 = At + (long long)srow * lda + lg;
  const unsigned short* a1 = At + (long long)(srow + 64) * lda + lg;
  const unsigned short* b0 = Bt + (long long)srow * ldb + lg;
  const unsigned short* b1 = Bt + (long long)(srow + 64) * ldb + lg;
  unsigned short* As0 = As + srow * 32 + scol;
  unsigned short* As1 = As + (srow + 64) * 32 + scol;
  unsigned short* Bs0 = Bs + srow * 32 + scol;
  unsigned short* Bs1 = Bs + (srow + 64) * 32 + scol;
  const int pg = (fq ^ ((fr >> 1) & 3)) << 3;
  for (int k0 = 0; k0 < K; k0 += 32) {
    __builtin_amdgcn_global_load_lds(AS1(a0 + k0), AS3(As0), 16, 0, 0);
    __builtin_amdgcn_global_load_lds(AS1(a1 + k0), AS3(As1), 16, 0, 0);
    __builtin_amdgcn_global_load_lds(AS1(b0 + k0), AS3(Bs0), 16, 0, 0);
    __builtin_amdgcn_global_load_lds(AS1(b1 + k0), AS3(Bs1), 16, 0, 0);
    __syncthreads();
    bf16x8 af[4], bfr[4];
#pragma unroll
    for (int i = 0; i < 4; i++)
      af[i] = *(const bf16x8*)(As + (wm + i * 16 + fr) * 32 + pg);
#pragma unroll
    for (int i = 0; i < 4; i++)
      bfr[i] = *(const bf16x8*)(Bs + (wn + i * 16 + fr) * 32 + pg);
#pragma unroll
    for (int mi = 0; mi < 4; mi++)
#pragma unroll
      for (int ni = 0; ni < 4; ni++)
        acc[mi][ni] = __builtin_amdgcn_mfma_f32_16x16x32_bf16(af[mi], bfr[ni], acc[mi][ni], 0, 0, 0);
    __syncthreads();
  }
}

// ---- LDS repack + coalesced bf16x8 store of one mi-slice (legacy) ---------
__device__ __forceinline__ void repack_store_mi(unsigned short (&vals)[4][4],
                                                unsigned short* sh, int mi,
                                                int m0, int n0, long long ldo,
                                                unsigned short* __restrict__ Out) {
  const int tid = threadIdx.x, lane = tid & 63, w = tid >> 6;
  const int half = w & 1, wn = (w >> 1) << 6;
  const int cl = lane & 15, q4 = lane >> 4;
  const int lr = half * 16 + q4 * 4;
#pragma unroll
  for (int ni = 0; ni < 4; ni++)
#pragma unroll
    for (int rr = 0; rr < 4; rr++)
      sh[(lr + rr) * 132 + wn + ni * 16 + cl] = vals[ni][rr];
  __syncthreads();
#pragma unroll
  for (int it = 0; it < 2; ++it) {
    int row = (tid >> 4) + it * 16;          // 0..31
    int c8 = (tid & 15) << 3;                // 0..120
    bf16x8 v = *(const bf16x8*)(sh + row * 132 + c8);
    int gr = m0 + (row < 16 ? mi * 16 + row : 48 + mi * 16 + row);
    *(bf16x8*)(Out + (long long)gr * ldo + n0 + c8) = v;
  }
  __syncthreads();
}

// ---------------------------------------------------------------------------
// 128x256-tile GEMM core. 512 threads = 8 waves (2 M x 4 N), per-wave 64x64
// output (acc[4][4]). BK=64/K-tile, 2 phases/K-tile (one per k-step of 32),
// 16 MFMA + 8 ds_read_b128 per phase, double-buffered LDS (96 KiB).
// LDS (shorts): buf b at b*24576:
//   A half h: h*4096   (rows 0-127 x 32 cols, row-major, 16B chunks swizzled)
//   B half h: 8192 + h*8192 (rows 0-255 x 32)
// Chunk swizzle: 16B chunk c stored at c ^ ((row>>1)&3); applied on the
// GLOBAL source (LDS dest linear, as global_load_lds requires) and on the
// ds_read address. Counted vmcnt(6) = one half-tile certified per phase;
// stages issued one half per phase -> sequential (tile,half) queue.
// C[m,n] = sum_k A[m,k]*B[n,k], A/B bf16 K-fast.
// ---------------------------------------------------------------------------
__device__ __forceinline__ void core8(
    const unsigned short* __restrict__ A, long long lda,
    const unsigned short* __restrict__ B, long long ldb,
    int nkt, f32x4 (&acc)[4][4], unsigned short* lds) {
  const int tid  = threadIdx.x;
  const int lane = tid & 63;
  const int w    = tid >> 6;
  const int wr   = w >> 2;            // 0..1
  const int wc   = w & 3;             // 0..3
  const int fr   = lane & 15;
  const int fq   = lane >> 4;
  const int csel = (fq ^ ((fr >> 1) & 3)) << 3;   // fragment chunk swizzle
  // staging: thread -> (row = tid>>2, 16B chunk = tid&3), source chunk swizzled
  const int srow = tid >> 2;                      // 0..127
  const int scsw = ((tid & 3) ^ ((srow >> 1) & 3)) << 3;
  const unsigned short* Asrc  = A + (long long)srow * lda + scsw;
  const unsigned short* Bsrc0 = B + (long long)srow * ldb + scsw;
  const unsigned short* Bsrc1 = B + (long long)(srow + 128) * ldb + scsw;
  unsigned short* dst0 = lds + tid * 8;           // per-thread 16B slot

#define STAGE(b_, kt_, h_)                                                       \
  do {                                                                           \
    const int ko_ = (kt_) * 64 + (h_) * 32;                                      \
    __builtin_amdgcn_global_load_lds(AS1(Asrc + ko_),                            \
        AS3(dst0 + (b_) * 24576 + (h_) * 4096), 16, 0, 0);                       \
    __builtin_amdgcn_global_load_lds(AS1(Bsrc0 + ko_),                           \
        AS3(dst0 + (b_) * 24576 + 8192 + (h_) * 8192), 16, 0, 0);                \
    __builtin_amdgcn_global_load_lds(AS1(Bsrc1 + ko_),                           \
        AS3(dst0 + (b_) * 24576 + 8192 + (h_) * 8192 + 4096), 16, 0, 0);         \
  } while (0)

  // prologue: tile0 both halves + tile1 half0 (9 loads); certify (0,h0)
  STAGE(0, 0, 0);
  STAGE(0, 0, 1);
  if (nkt > 1) {
    STAGE(1, 1, 0);
    asm volatile("s_waitcnt vmcnt(6)" ::: "memory");
  } else {
    asm volatile("s_waitcnt vmcnt(3)" ::: "memory");
  }
  __builtin_amdgcn_s_barrier();
  __builtin_amdgcn_sched_barrier(0);

  const unsigned short* Ard = lds + (wr * 64 + fr) * 32 + csel;
  const unsigned short* Brd = lds + 8192 + (wc * 64 + fr) * 32 + csel;

#pragma unroll 1
  for (int kt = 0; kt < nkt; ++kt) {
    const int bo = (kt & 1) * 24576;
    const unsigned short* Ab = Ard + bo;
    const unsigned short* Bb = Brd + bo;
    bf16x8 af[4], bf[4];
    // ---------------- phase 1: k-half 0 ----------------
#pragma unroll
    for (int mi = 0; mi < 4; ++mi) af[mi] = *(const bf16x8*)(Ab + mi * 512);
#pragma unroll
    for (int nj = 0; nj < 4; ++nj) bf[nj] = *(const bf16x8*)(Bb + nj * 512);
    if (kt + 1 < nkt) {
      STAGE((kt + 1) & 1, kt + 1, 1);
      asm volatile("s_waitcnt vmcnt(6)" ::: "memory");   // (kt,h1) landed
    } else {
      asm volatile("s_waitcnt vmcnt(0)" ::: "memory");
    }
    __builtin_amdgcn_s_barrier();
    asm volatile("s_waitcnt lgkmcnt(0)" ::: "memory");
    __builtin_amdgcn_sched_barrier(0);
    __builtin_amdgcn_s_setprio(1);
#pragma unroll
    for (int mi = 0; mi < 4; ++mi)
#pragma unroll
      for (int nj = 0; nj < 4; ++nj)
        acc[mi][nj] = __builtin_amdgcn_mfma_f32_16x16x32_bf16(af[mi], bf[nj], acc[mi][nj], 0, 0, 0);
    __builtin_amdgcn_s_setprio(0);
    __builtin_amdgcn_s_barrier();
    __builtin_amdgcn_sched_barrier(0);
    // ---------------- phase 2: k-half 1 ----------------
#pragma unroll
    for (int mi = 0; mi < 4; ++mi) af[mi] = *(const bf16x8*)(Ab + 4096 + mi * 512);
#pragma unroll
    for (int nj = 0; nj < 4; ++nj) bf[nj] = *(const bf16x8*)(Bb + 8192 + nj * 512);
    if (kt + 2 < nkt) {
      STAGE(kt & 1, kt + 2, 0);
      asm volatile("s_waitcnt vmcnt(6)" ::: "memory");   // (kt+1,h0) landed
    } else if (kt + 1 < nkt) {
      asm volatile("s_waitcnt vmcnt(3)" ::: "memory");
    }
    __builtin_amdgcn_s_barrier();
    asm volatile("s_waitcnt lgkmcnt(0)" ::: "memory");
    __builtin_amdgcn_sched_barrier(0);
    __builtin_amdgcn_s_setprio(1);
#pragma unroll
    for (int mi = 0; mi < 4; ++mi)
#pragma unroll
      for (int nj = 0; nj < 4; ++nj)
        acc[mi][nj] = __builtin_amdgcn_mfma_f32_16x16x32_bf16(af[mi], bf[nj], acc[mi][nj], 0, 0, 0);
    __builtin_amdgcn_s_setprio(0);
    __builtin_amdgcn_s_barrier();
    __builtin_amdgcn_sched_barrier(0);
  }
#undef STAGE
}

// ---- Q/K/V projections; Q/K get RoPE; V computed AS Vt (swapped operands) -
// Grid (64, 4, 3), 512 threads. Q/K: x=m-tile(128), y=n-tile(256).
// V: flat = x*4+y in [0,256): m-tile(d) = flat&7, n-tile(s) = flat>>3.
__global__ __launch_bounds__(512, 2) void proj_rope(
    const unsigned short* __restrict__ xb,
    const unsigned short* __restrict__ Wq, const unsigned short* __restrict__ Wk,
    const unsigned short* __restrict__ Wv,
    const float* __restrict__ bq, const float* __restrict__ bk, const float* __restrict__ bv,
    unsigned short* __restrict__ Q, unsigned short* __restrict__ Ko,
    unsigned short* __restrict__ Vt) {
  __shared__ unsigned short lds[49152];   // 96 KiB: GEMM dbuf, then repack
  const int which = blockIdx.z;
  const int tid = threadIdx.x, lane = tid & 63, w = tid >> 6;
  const int wr = w >> 2, wc = w & 3;
  const int cl = lane & 15, q4 = lane >> 4;

  f32x4 acc[4][4];
#pragma unroll
  for (int i = 0; i < 4; i++)
#pragma unroll
    for (int j = 0; j < 4; j++)
#pragma unroll
      for (int k = 0; k < 4; k++) acc[i][j][k] = 0.0f;

  if (which == 2) {
    // ---- V path: Vt[d,s] = sum_k Wv[d,k] x[s,k]; A = Wv (m=d), B = x (n=s)
    const int flat = blockIdx.x * 4 + blockIdx.y;   // 0..255
    const int m0 = (flat & 7) * 128;                // d tile
    const int n0 = (flat >> 3) * 256;               // global s tile
    core8(Wv + (long long)m0 * 1024, 1024, xb + (long long)n0 * 1024, 1024, 16, acc, lds);
    __syncthreads();
    const int b = n0 >> 11, sloc = n0 & 2047;
#pragma unroll
    for (int mi = 0; mi < 4; ++mi) {
      const int lr = wr * 64 + mi * 16 + q4 * 4;
#pragma unroll
      for (int rr = 0; rr < 4; ++rr) {
        const float b_ = bv[m0 + lr + rr];          // bias per d-row
#pragma unroll
        for (int nj = 0; nj < 4; ++nj)
          lds[(lr + rr) * 264 + wc * 64 + nj * 16 + cl] = f2bf(acc[mi][nj][rr] + b_);
      }
    }
    __syncthreads();
    unsigned short* Outb = Vt + (long long)b * 1024 * 2048;
#pragma unroll
    for (int it = 0; it < 8; ++it) {
      int c = it * 512 + tid;
      int row = c >> 5, c8 = (c & 31) << 3;
      bf16x8 v = *(const bf16x8*)(lds + row * 264 + c8);
      *(bf16x8*)(Outb + (long long)(m0 + row) * 2048 + sloc + c8) = v;
    }
    return;
  }

  // ---- Q/K path: bias + RoPE (native sin/cos) ----
  const int m0 = blockIdx.x * 128;    // token rows
  const int n0 = blockIdx.y * 256;    // feature cols
  const unsigned short* W = which == 0 ? Wq : Wk;
  const float* bias = which == 0 ? bq : bk;
  unsigned short* Out = which == 0 ? Q : Ko;

  core8(xb + (long long)m0 * 1024, 1024, W + (long long)n0 * 1024, 1024, 16, acc, lds);
  __syncthreads();

  const float NEG_L2T_512 = -0.025952563239354392f;  // -log2(10000)/512
  const float INV2PI = 0.15915494309189535f;
  float freqn[4];
#pragma unroll
  for (int nj = 0; nj < 4; ++nj) {
    int gn = n0 + wc * 64 + nj * 16 + cl;
    freqn[nj] = exp2f(NEG_L2T_512 * (float)(gn >> 1));
  }
#pragma unroll
  for (int mi = 0; mi < 4; ++mi) {
    const int lr = wr * 64 + mi * 16 + q4 * 4;
    const int t0 = (m0 & 2047) + lr;   // batch-local time (tiles never straddle)
#pragma unroll
    for (int nj = 0; nj < 4; ++nj) {
      const int gn = n0 + wc * 64 + nj * 16 + cl;
      const float bi = bias[gn];
#pragma unroll
      for (int rr = 0; rr < 4; ++rr) {
        float v = acc[mi][nj][rr] + bi;
        float partner = __shfl_xor(v, 1, 64);
        float ang = (float)(t0 + rr) * freqn[nj];
        float rev = ang * INV2PI;
        rev = rev - floorf(rev);           // v_sin/v_cos domain
        float c_ = __builtin_amdgcn_cosf(rev);
        float s_ = __builtin_amdgcn_sinf(rev);
        v = v * c_ + ((gn & 1) ? partner : -partner) * s_;
        lds[(lr + rr) * 264 + wc * 64 + nj * 16 + cl] = f2bf(v);
      }
    }
  }
  __syncthreads();
#pragma unroll
  for (int it = 0; it < 8; ++it) {
    int c = it * 512 + tid;
    int row = c >> 5, c8 = (c & 31) << 3;
    bf16x8 v = *(const bf16x8*)(lds + row * 264 + c8);
    *(bf16x8*)(Out + (long long)(m0 + row) * 1024 + n0 + c8) = v;
  }
}

// ---- P = exp(Q K^T / sqrt(C)) (causal-zeroed), bf16; row sums via atomics -
__global__ __launch_bounds__(256) void score_exp(const unsigned short* __restrict__ Q,
                                                 const unsigned short* __restrict__ Kk,
                                                 unsigned short* __restrict__ P,
                                                 float* __restrict__ row_sum) {
  __shared__ unsigned short sh[8192];
  const int bx = blockIdx.x;
  int i = (int)((sqrtf(8.0f * (float)bx + 1.0f) - 1.0f) * 0.5f);
  while ((i + 1) * (i + 2) / 2 <= bx) ++i;
  while (i * (i + 1) / 2 > bx) --i;
  const int j = bx - i * (i + 1) / 2;       // 0..i
  const int b = blockIdx.z;
  const int m0 = i * 128, n0 = j * 128;
  const unsigned short* Qb = Q + (long long)b * 2048 * 1024;
  const unsigned short* Kb = Kk + (long long)b * 2048 * 1024;
  unsigned short* Pb = P + (long long)b * 2048 * 2048;
  float* rs = row_sum + b * 2048;

  f32x4 acc[4][4];
#pragma unroll
  for (int ii = 0; ii < 4; ii++)
#pragma unroll
    for (int jj = 0; jj < 4; jj++)
#pragma unroll
      for (int k = 0; k < 4; k++) acc[ii][jj][k] = 0.0f;

  gemm_core(Qb + (long long)m0 * 1024, 1024, Kb + (long long)n0 * 1024, 1024, 1024, acc, sh, sh + 4096);

  const int tid = threadIdx.x, lane = tid & 63, w = tid >> 6;
  const int wm = (w & 1) << 6, wn = (w >> 1) << 6;
  const int cl = lane & 15, q4 = lane >> 4;
  const bool diag = (i == j);
#pragma unroll
  for (int mi = 0; mi < 4; mi++) {
    unsigned short vals[4][4];
    float rsum[4] = {0.f, 0.f, 0.f, 0.f};
#pragma unroll
    for (int ni = 0; ni < 4; ni++) {
      const int gn = n0 + wn + ni * 16 + cl;
#pragma unroll
      for (int rr = 0; rr < 4; rr++) {
        const int gm = m0 + wm + mi * 16 + q4 * 4 + rr;
        float e = (diag && gn > gm) ? 0.0f : __expf(acc[mi][ni][rr] * 0.03125f);
        vals[ni][rr] = f2bf(e);
        rsum[rr] += e;
      }
    }
#pragma unroll
    for (int rr = 0; rr < 4; rr++) {
#pragma unroll
      for (int off = 1; off < 16; off <<= 1) rsum[rr] += __shfl_xor(rsum[rr], off, 64);
    }
    if (cl == 0) {
      const int gm = m0 + wm + mi * 16 + q4 * 4;
#pragma unroll
      for (int rr = 0; rr < 4; rr++) atomicAdd(&rs[gm + rr], rsum[rr]);
    }
    repack_store_mi(vals, sh, mi, m0, n0, 2048, Pb);
  }
}

// ---- O = (P V) / row_sum; longest-K blocks dispatched first ---------------
__global__ __launch_bounds__(256) void pv_gemm(const unsigned short* __restrict__ P,
                                               const unsigned short* __restrict__ Vt,
                                               const float* __restrict__ row_sum,
                                               unsigned short* __restrict__ O) {
  __shared__ unsigned short sh[8192];
  const int b = blockIdx.z;
  const int mt = 15 - blockIdx.x;   // longest K first (tail balance)
  const int m0 = mt * 128;          // t tile
  const int n0 = blockIdx.y * 128;  // d tile
  const unsigned short* Pb = P + (long long)b * 2048 * 2048;
  const unsigned short* Vb = Vt + (long long)b * 1024 * 2048;
  const float* rs = row_sum + b * 2048;
  const int K = m0 + 128;  // causal: P[t, s>t] == 0 beyond this

  f32x4 acc[4][4];
#pragma unroll
  for (int i = 0; i < 4; i++)
#pragma unroll
    for (int j = 0; j < 4; j++)
#pragma unroll
      for (int k = 0; k < 4; k++) acc[i][j][k] = 0.0f;

  gemm_core(Pb + (long long)m0 * 2048, 2048, Vb + (long long)n0 * 2048, 2048, K, acc, sh, sh + 4096);

  const int tid = threadIdx.x, lane = tid & 63, w = tid >> 6;
  const int wm = (w & 1) << 6;
  const int q4 = lane >> 4;
#pragma unroll
  for (int mi = 0; mi < 4; mi++) {
    unsigned short vals[4][4];
    float inv[4];
    const int gm0 = m0 + wm + mi * 16 + q4 * 4;
#pragma unroll
    for (int rr = 0; rr < 4; rr++) inv[rr] = 1.0f / rs[gm0 + rr];
#pragma unroll
    for (int ni = 0; ni < 4; ni++)
#pragma unroll
      for (int rr = 0; rr < 4; rr++)
        vals[ni][rr] = f2bf(acc[mi][ni][rr] * inv[rr]);
    repack_store_mi(vals, sh, mi, m0, n0, 1024, O + (long long)b * 2048 * 1024);
  }
}

// ---- out = O Wf^T + bf, fp32 out (128x256 core, 512 thr) ------------------
__global__ __launch_bounds__(512, 2) void final_gemm(const unsigned short* __restrict__ O,
                                                     const unsigned short* __restrict__ Wf,
                                                     const float* __restrict__ bf_,
                                                     float* __restrict__ out) {
  __shared__ unsigned short lds[49152];
  float* shf = (float*)lds;
  const int tid = threadIdx.x, lane = tid & 63, w = tid >> 6;
  const int wr = w >> 2, wc = w & 3;
  const int cl = lane & 15, q4 = lane >> 4;
  const int m0 = blockIdx.x * 128;
  const int n0 = blockIdx.y * 256;

  f32x4 acc[4][4];
#pragma unroll
  for (int i = 0; i < 4; i++)
#pragma unroll
    for (int j = 0; j < 4; j++)
#pragma unroll
      for (int k = 0; k < 4; k++) acc[i][j][k] = 0.0f;

  core8(O + (long long)m0 * 1024, 1024, Wf + (long long)n0 * 1024, 1024, 16, acc, lds);

  // fp32 repack in two 64-row rounds (64 x 260 floats = 66.5 KB <= 96 KB)
#pragma unroll
  for (int r = 0; r < 2; ++r) {
    __syncthreads();
    if (wr == r) {
#pragma unroll
      for (int mi = 0; mi < 4; ++mi)
#pragma unroll
        for (int nj = 0; nj < 4; ++nj) {
          const int col = wc * 64 + nj * 16 + cl;
          const float bi = bf_[n0 + col];
#pragma unroll
          for (int rr = 0; rr < 4; ++rr)
            shf[(mi * 16 + q4 * 4 + rr) * 260 + col] = acc[mi][nj][rr] + bi;
        }
    }
    __syncthreads();
#pragma unroll
    for (int it = 0; it < 8; ++it) {
      int c = it * 512 + tid;
      int row = c >> 6, c4 = (c & 63) << 2;
      float4 v = *(const float4*)(shf + row * 260 + c4);
      *(float4*)(out + (long long)(m0 + r * 64 + row) * 1024 + n0 + c4) = v;
    }
  }
}

// ---------------------------------------------------------------------------
extern "C" void kernel_launch(void* const* d_in, const int* in_sizes, int n_in,
                              void* d_out, int out_size, void* d_ws, size_t ws_size,
                              hipStream_t stream) {
  (void)in_sizes; (void)n_in; (void)out_size; (void)ws_size;
  const float* x   = (const float*)d_in[0];
  const float* Wq  = (const float*)d_in[1];
  const float* bq  = (const float*)d_in[2];
  const float* Wk  = (const float*)d_in[3];
  const float* bk  = (const float*)d_in[4];
  const float* Wv  = (const float*)d_in[5];
  const float* bv  = (const float*)d_in[6];
  const float* Wf  = (const float*)d_in[7];
  const float* bf_ = (const float*)d_in[8];
  float* out = (float*)d_out;

  char* ws = (char*)d_ws;
  const size_t MB = 1024 * 1024;
  unsigned short* xb  = (unsigned short*)(ws);             // 16 MB
  unsigned short* Wqb = (unsigned short*)(ws + 16 * MB);   // 2 MB
  unsigned short* Wkb = (unsigned short*)(ws + 18 * MB);   // 2 MB
  unsigned short* Wvb = (unsigned short*)(ws + 20 * MB);   // 2 MB
  unsigned short* Wfb = (unsigned short*)(ws + 22 * MB);   // 2 MB
  unsigned short* Qb  = (unsigned short*)(ws + 24 * MB);   // 16 MB
  unsigned short* Kb  = (unsigned short*)(ws + 40 * MB);   // 16 MB
  unsigned short* Vtb = (unsigned short*)(ws + 56 * MB);   // 16 MB
  unsigned short* Ob  = (unsigned short*)(ws + 72 * MB);   // 16 MB
  unsigned short* Pb  = (unsigned short*)(ws + 88 * MB);   // 32 MB P bf16
  float*          rsum= (float*)(ws + 120 * MB);           // 32 KB row sums

  hipMemsetAsync(rsum, 0, 8192 * sizeof(float), stream);
  cast_all<<<dim3(3145728 / 256), dim3(256), 0, stream>>>(x, Wq, Wk, Wv, Wf, xb, Wqb, Wkb, Wvb, Wfb);
  proj_rope<<<dim3(64, 4, 3), dim3(512), 0, stream>>>(xb, Wqb, Wkb, Wvb, bq, bk, bv, Qb, Kb, Vtb);
  score_exp<<<dim3(136, 1, 4), dim3(256), 0, stream>>>(Qb, Kb, Pb, rsum);
  pv_gemm<<<dim3(16, 8, 4), dim3(256), 0, stream>>>(Pb, Vtb, rsum, Ob);
  final_gemm<<<dim3(64, 4), dim3(512), 0, stream>>>(Ob, Wfb, bf_, out);
}